// Round 6
// baseline (582.471 us; speedup 1.0000x reference)
//
#include <hip/hip_runtime.h>
#include <hip/hip_bf16.h>

#define VOCAB 512
#define EMB   128
#define HID   64
#define BATCH 256
#define TLEN  1024
#define CH    16              // steps per chunk
#define NCH   (TLEN / CH)     // 64 chunks
#define RS    128             // ring depth in steps (8 chunks)
#define RCH   (RS / CH)       // 8 chunks per ring

__device__ __forceinline__ float fast_tanh(float x) {
    // tanh(x) = 1 - 2/(exp(2x)+1); exact at both saturated ends.
    float e = __expf(2.0f * x);
    return 1.0f - 2.0f / (e + 1.0f);
}

// Broadcast lane j's value of v to all lanes via SGPR (private VALU pipe,
// NOT the shared DS pipe — R5 post-mortem: 3 waves x 16 ds_read_b128
// broadcasts/step saturated the CU's single LDS pipe at ~774 cyc/step).
__device__ __forceinline__ float rl(float v, int j) {
    return __int_as_float(__builtin_amdgcn_readlane(__float_as_int(v), j));
}

// dot(w_row, broadcast(hv)) + init. Accumulator grouping (j mod 4, combined
// as (a0+a2)+(a1+a3)) is bitwise-identical to R5's v2f version -> absmax 0.
__device__ __forceinline__ float dot64(const float* w, float hv, float init) {
    float a0 = init, a1 = 0.f, a2 = 0.f, a3 = 0.f;
    #pragma unroll
    for (int q = 0; q < 16; ++q) {
        a0 = fmaf(rl(hv, 4 * q + 0), w[4 * q + 0], a0);
        a1 = fmaf(rl(hv, 4 * q + 1), w[4 * q + 1], a1);
        a2 = fmaf(rl(hv, 4 * q + 2), w[4 * q + 2], a2);
        a3 = fmaf(rl(hv, 4 * q + 3), w[4 * q + 3], a3);
    }
    return (a0 + a2) + (a1 + a3);
}

// LDS-only fence: drains DS queue WITHOUT vmcnt -> global prefetches live on.
__device__ __forceinline__ void lds_fence() {
    asm volatile("s_waitcnt lgkmcnt(0)" ::: "memory");
}
__device__ __forceinline__ void compiler_fence() {
    asm volatile("" ::: "memory");
}

// ---------------------------------------------------------------------------
// Kernel 1: P0[v][i] = sum_e emb[v][e]*Wih0[i][e] + bih0[i] + bhh0[i]  (fp32)
// ---------------------------------------------------------------------------
__global__ void __launch_bounds__(64) p0_kernel(
    const float* __restrict__ emb,
    const float* __restrict__ wih0,
    const float* __restrict__ bih0,
    const float* __restrict__ bhh0,
    float* __restrict__ P0)
{
    const int v = blockIdx.x;
    const int i = threadIdx.x;
    const float4* er = (const float4*)(emb  + v * EMB);
    const float4* wr = (const float4*)(wih0 + i * EMB);
    float a0 = 0.f, a1 = 0.f, a2 = 0.f, a3 = 0.f;
    #pragma unroll
    for (int k = 0; k < EMB / 4; ++k) {
        float4 e4 = er[k];
        float4 w4 = wr[k];
        a0 = fmaf(e4.x, w4.x, a0);
        a1 = fmaf(e4.y, w4.y, a1);
        a2 = fmaf(e4.z, w4.z, a2);
        a3 = fmaf(e4.w, w4.w, a3);
    }
    P0[v * HID + i] = (a0 + a1) + (a2 + a3) + bih0[i] + bhh0[i];
}

// ---------------------------------------------------------------------------
// Kernel 2: decoupled 3-wave pipeline (R5 structure) with readlane broadcast.
//   wave0: h0[t] = tanh(P0[x[t]] + Whh0 h0[t-1])   h0 register-resident
//   wave1: p1[t] = b1 + Wih1 h0[t]                  1 pipelined b32 read/step
//   wave2: h1[t] = tanh(p1[t] + Whh1 h1[t-1])       h1 register-resident
// DS traffic: ~4 b32 ops/step total (R5: ~51 incl. 48 b128 broadcasts).
// Sync: per-chunk LDS flags, lgkmcnt-only fences, zero barriers in the loop.
// ---------------------------------------------------------------------------
__global__ void __launch_bounds__(192, 1) rnn_kernel(
    const int*   __restrict__ xs,
    const float* __restrict__ P0,
    const float* __restrict__ Whh0,
    const float* __restrict__ Wih1,
    const float* __restrict__ Whh1,
    const float* __restrict__ bih1,
    const float* __restrict__ bhh1,
    const float* __restrict__ W1,
    const float* __restrict__ b1,
    const float* __restrict__ W2,
    const float* __restrict__ b2,
    float*       __restrict__ out)
{
    __shared__ float h0ring[RS][HID];   // 32 KiB
    __shared__ float p1ring[RS][HID];   // 32 KiB
    __shared__ int   xlds[TLEN];        // 4 KiB
    __shared__ int   flags[3];

    const int b    = blockIdx.x;
    const int tid  = threadIdx.x;
    const int wv   = tid >> 6;
    const int lane = tid & 63;

    const int* xrow = xs + b * TLEN;

    if (wv == 0) {
        #pragma unroll
        for (int i = 0; i < TLEN / 64; ++i)
            xlds[lane + 64 * i] = xrow[lane + 64 * i];
    }
    if (tid < 3) flags[tid] = 0;
    __syncthreads();                     // the ONLY barrier in the kernel

    // Per-wave weight row -> 64 resident VGPRs (proven regime: VGPR~88)
    const float* wmat = (wv == 0) ? Whh0 : (wv == 1) ? Wih1 : Whh1;
    float w[HID];
    {
        const float4* wr = (const float4*)(wmat + lane * HID);
        #pragma unroll
        for (int k = 0; k < 16; ++k) {
            float4 u = wr[k];
            w[4 * k + 0] = u.x; w[4 * k + 1] = u.y;
            w[4 * k + 2] = u.z; w[4 * k + 3] = u.w;
        }
    }

    volatile int* vf = (volatile int*)flags;

    if (wv == 0) {
        // ---- layer-0 recurrence: h0 lives in a register ----
        float h0v   = 0.f;
        float a_pre = P0[xrow[0] * HID + lane];
        float a_nxt = P0[xrow[1] * HID + lane];
        #pragma unroll 1
        for (int k = 0; k < NCH; ++k) {
            if (k >= RCH) {
                while (vf[1] < k - (RCH - 1)) {}
                compiler_fence();
            }
            const int base = (k & (RCH - 1)) * CH;
            #pragma unroll 1
            for (int i = 0; i < CH; ++i) {
                const int t   = k * CH + i;
                const int pix = (t + 2 < TLEN) ? (t + 2) : (TLEN - 1);
                float a_n2 = P0[xlds[pix] * HID + lane];   // prefetch t+2
                h0v = fast_tanh(dot64(w, h0v, a_pre));
                h0ring[base + i][lane] = h0v;              // 1 DS write/step
                a_pre = a_nxt;
                a_nxt = a_n2;
            }
            lds_fence();                 // DS only — vmcnt untouched
            if (lane == 0) vf[0] = k + 1;
        }
    } else if (wv == 1) {
        // ---- layer-1 input projection (no recurrence) ----
        const float b1s = bih1[lane] + bhh1[lane];
        #pragma unroll 1
        for (int k = 0; k < NCH; ++k) {
            while (vf[0] < k + 1) {}
            if (k >= RCH) { while (vf[2] < k - (RCH - 1)) {} }
            compiler_fence();
            const int base = (k & (RCH - 1)) * CH;
            float hvA = h0ring[base][lane];
            #pragma unroll 1
            for (int i = 0; i < CH; i += 2) {
                float hvB = h0ring[base + i + 1][lane];        // pipelined
                p1ring[base + i][lane] = dot64(w, hvA, b1s);
                hvA = h0ring[base + ((i + 2) & (CH - 1))][lane]; // wraps to
                p1ring[base + i + 1][lane] = dot64(w, hvB, b1s); // safe slot
            }
            lds_fence();
            if (lane == 0) vf[1] = k + 1;
        }
    } else {
        // ---- layer-1 recurrence: h1 lives in a register ----
        float h1v = 0.f;
        #pragma unroll 1
        for (int k = 0; k < NCH; ++k) {
            while (vf[1] < k + 1) {}
            compiler_fence();
            const int base = (k & (RCH - 1)) * CH;
            float pvA = p1ring[base][lane];
            #pragma unroll 1
            for (int i = 0; i < CH; i += 2) {
                float pvB = p1ring[base + i + 1][lane];        // pipelined
                h1v = fast_tanh(dot64(w, h1v, pvA));
                pvA = p1ring[base + ((i + 2) & (CH - 1))][lane];
                h1v = fast_tanh(dot64(w, h1v, pvB));
            }
            lds_fence();                 // reads consumed before publish
            if (lane == 0) vf[2] = k + 1;
        }
        // ---- MLP head: y = relu(h1 @ W1^T + b1) @ W2^T + b2 ----
        float r = 0.f;
        if (lane < 32) {
            float acc = b1[lane];
            const float* w1r = W1 + lane * HID;
            #pragma unroll
            for (int j = 0; j < HID; ++j)
                acc = fmaf(w1r[j], rl(h1v, j), acc);   // readlane ignores exec
            r = fmaxf(acc, 0.f) * W2[lane];
        }
        #pragma unroll
        for (int off = 32; off > 0; off >>= 1) r += __shfl_down(r, off);
        if (lane == 0) out[b] = r + b2[0];
    }
}

extern "C" void kernel_launch(void* const* d_in, const int* in_sizes, int n_in,
                              void* d_out, int out_size, void* d_ws, size_t ws_size,
                              hipStream_t stream)
{
    const int*   x    = (const int*)d_in[0];
    const float* emb  = (const float*)d_in[1];
    const float* Wih0 = (const float*)d_in[2];
    const float* Whh0 = (const float*)d_in[3];
    const float* bih0 = (const float*)d_in[4];
    const float* bhh0 = (const float*)d_in[5];
    const float* Wih1 = (const float*)d_in[6];
    const float* Whh1 = (const float*)d_in[7];
    const float* bih1 = (const float*)d_in[8];
    const float* bhh1 = (const float*)d_in[9];
    const float* W1   = (const float*)d_in[10];
    const float* b1   = (const float*)d_in[11];
    const float* W2   = (const float*)d_in[12];
    const float* b2   = (const float*)d_in[13];

    float* P0 = (float*)d_ws;   // 512*64*4 = 128 KiB scratch

    hipLaunchKernelGGL(p0_kernel, dim3(VOCAB), dim3(HID), 0, stream,
                       emb, Wih0, bih0, bhh0, P0);
    hipLaunchKernelGGL(rnn_kernel, dim3(BATCH), dim3(192), 0, stream,
                       x, P0, Whh0, Wih1, Whh1, bih1, bhh1,
                       W1, b1, W2, b2, (float*)d_out);
}

// Round 7
// 393.529 us; speedup vs baseline: 1.4801x; 1.4801x over previous
//
#include <hip/hip_runtime.h>
#include <hip/hip_bf16.h>

#define VOCAB 512
#define EMB   128
#define HID   64
#define BATCH 256
#define TLEN  1024
#define CH    16              // steps per chunk
#define NCH   (TLEN / CH)     // 64 chunks
#define RS    128             // ring depth in steps (8 chunks)
#define RCH   (RS / CH)       // 8 chunks per ring

typedef float v2f __attribute__((ext_vector_type(2)));

__device__ __forceinline__ float fast_tanh(float x) {
    // tanh(x) = 1 - 2/(exp(2x)+1); exact at both saturated ends.
    float e = __expf(2.0f * x);
    return 1.0f - 2.0f / (e + 1.0f);
}

// LDS-only fence: drains DS queue WITHOUT vmcnt -> global prefetches live on.
__device__ __forceinline__ void lds_fence() {
    asm volatile("s_waitcnt lgkmcnt(0)" ::: "memory");
}
__device__ __forceinline__ void compiler_fence() {
    asm volatile("" ::: "memory");
}
// Spin-wait throttle: ~64 cyc sleep so polls don't hammer the shared DS pipe
// (R6 post-mortem: tight ds_read_b32 poll loops steal DS slots from the
// producing wave — the pipe all three waves' broadcasts also need).
__device__ __forceinline__ void nap() { __builtin_amdgcn_s_sleep(1); }

// ---------------------------------------------------------------------------
// Kernel 1: P0[v][i] = sum_e emb[v][e]*Wih0[i][e] + bih0[i] + bhh0[i]  (fp32)
// ---------------------------------------------------------------------------
__global__ void __launch_bounds__(64) p0_kernel(
    const float* __restrict__ emb,
    const float* __restrict__ wih0,
    const float* __restrict__ bih0,
    const float* __restrict__ bhh0,
    float* __restrict__ P0)
{
    const int v = blockIdx.x;
    const int i = threadIdx.x;
    const float4* er = (const float4*)(emb  + v * EMB);
    const float4* wr = (const float4*)(wih0 + i * EMB);
    float a0 = 0.f, a1 = 0.f, a2 = 0.f, a3 = 0.f;
    #pragma unroll
    for (int k = 0; k < EMB / 4; ++k) {
        float4 e4 = er[k];
        float4 w4 = wr[k];
        a0 = fmaf(e4.x, w4.x, a0);
        a1 = fmaf(e4.y, w4.y, a1);
        a2 = fmaf(e4.z, w4.z, a2);
        a3 = fmaf(e4.w, w4.w, a3);
    }
    P0[v * HID + i] = (a0 + a1) + (a2 + a3) + bih0[i] + bhh0[i];
}

// ---------------------------------------------------------------------------
// Kernel 2: decoupled 3-wave pipeline (R5 structure — proven 330 us) with
// DS-pipe pressure fixes:
//   - spin loops throttled by s_sleep (no DS hammering)
//   - x[] indices read via wave-uniform global load -> scalar pipe, not DS
//   wave0: h0[t] = tanh(P0[x[t]] + Whh0 h0[t-1])      (recurrent)
//   wave1: p1[t] = b1 + Wih1 h0[t]                     (no recurrence)
//   wave2: h1[t] = tanh(p1[t] + Whh1 h1[t-1])          (recurrent)
// 64 weight floats/lane per wave (proven register-resident regime, VGPR~88).
// Sync: per-chunk LDS flags, lgkmcnt-only fences, zero barriers in the loop.
// ---------------------------------------------------------------------------
__global__ void __launch_bounds__(192, 1) rnn_kernel(
    const int*   __restrict__ xs,
    const float* __restrict__ P0,
    const float* __restrict__ Whh0,
    const float* __restrict__ Wih1,
    const float* __restrict__ Whh1,
    const float* __restrict__ bih1,
    const float* __restrict__ bhh1,
    const float* __restrict__ W1,
    const float* __restrict__ b1,
    const float* __restrict__ W2,
    const float* __restrict__ b2,
    float*       __restrict__ out)
{
    __shared__ float h0ring[RS][HID];   // 32 KiB
    __shared__ float p1ring[RS][HID];   // 32 KiB
    __shared__ float h1buf[2][HID];
    __shared__ int   flags[3];

    const int b    = blockIdx.x;
    const int tid  = threadIdx.x;
    const int wv   = tid >> 6;
    const int lane = tid & 63;

    const int* xrow = xs + b * TLEN;

    if (wv == 0) {
        h0ring[RS - 1][lane] = 0.f;      // h0[-1] = 0
    } else if (wv == 2) {
        h1buf[0][lane] = 0.f;            // h1[-1] = 0
        h1buf[1][lane] = 0.f;
    }
    if (tid < 3) flags[tid] = 0;
    __syncthreads();                     // the ONLY barrier in the kernel

    // Per-wave weight row -> 32 packed v2f (64 VGPRs), loop-invariant.
    const float* wmat = (wv == 0) ? Whh0 : (wv == 1) ? Wih1 : Whh1;
    v2f w[32];
    {
        const float4* wr = (const float4*)(wmat + lane * HID);
        #pragma unroll
        for (int k = 0; k < 16; ++k) {
            float4 u = wr[k];
            w[2 * k]     = v2f{u.x, u.y};
            w[2 * k + 1] = v2f{u.z, u.w};
        }
    }

    volatile int* vf = (volatile int*)flags;

    if (wv == 0) {
        // ---- layer-0 recurrence ----
        float a_pre = P0[xrow[0] * HID + lane];
        float a_nxt = P0[xrow[1] * HID + lane];
        #pragma unroll 1
        for (int k = 0; k < NCH; ++k) {
            if (k >= RCH) {                       // slot reuse guard
                while (vf[1] < k - (RCH - 1)) nap();
                compiler_fence();
            }
            const int base = (k & (RCH - 1)) * CH;
            const int t0   = k * CH;
            #pragma unroll
            for (int i = 0; i < CH; ++i) {
                const int t   = t0 + i;
                const int pix = (t + 2 < TLEN) ? (t + 2) : (TLEN - 1);
                // wave-uniform index -> scalar (s_load) path, not DS
                float a_n2 = P0[xrow[pix] * HID + lane];   // prefetch t+2
                const float4* hp = (const float4*)h0ring[(base + i - 1) & (RS - 1)];
                v2f ac0 = v2f{a_pre, 0.f}, ac1 = v2f{0.f, 0.f};
                #pragma unroll
                for (int q = 0; q < 16; ++q) {
                    float4 hv = hp[q];
                    ac0 = __builtin_elementwise_fma(v2f{hv.x, hv.y}, w[2*q],   ac0);
                    ac1 = __builtin_elementwise_fma(v2f{hv.z, hv.w}, w[2*q+1], ac1);
                }
                h0ring[base + i][lane] =
                    fast_tanh((ac0.x + ac1.x) + (ac0.y + ac1.y));
                a_pre = a_nxt;
                a_nxt = a_n2;
            }
            lds_fence();                          // DS queue only, NOT vmcnt
            if (lane == 0) vf[0] = k + 1;
        }
    } else if (wv == 1) {
        // ---- layer-1 input projection (no recurrence: pure throughput) ----
        const float b1s = bih1[lane] + bhh1[lane];
        #pragma unroll 1
        for (int k = 0; k < NCH; ++k) {
            while (vf[0] < k + 1) nap();
            if (k >= RCH) { while (vf[2] < k - (RCH - 1)) nap(); }
            compiler_fence();
            const int base = (k & (RCH - 1)) * CH;
            #pragma unroll
            for (int i = 0; i < CH; ++i) {
                const float4* hp = (const float4*)h0ring[base + i];
                v2f ac0 = v2f{b1s, 0.f}, ac1 = v2f{0.f, 0.f};
                #pragma unroll
                for (int q = 0; q < 16; ++q) {
                    float4 hv = hp[q];
                    ac0 = __builtin_elementwise_fma(v2f{hv.x, hv.y}, w[2*q],   ac0);
                    ac1 = __builtin_elementwise_fma(v2f{hv.z, hv.w}, w[2*q+1], ac1);
                }
                p1ring[base + i][lane] = (ac0.x + ac1.x) + (ac0.y + ac1.y);
            }
            lds_fence();
            if (lane == 0) vf[1] = k + 1;
        }
    } else {
        // ---- layer-1 recurrence ----
        #pragma unroll 1
        for (int k = 0; k < NCH; ++k) {
            while (vf[1] < k + 1) nap();
            compiler_fence();
            const int base = (k & (RCH - 1)) * CH;
            float p[CH];                           // prefetch whole chunk
            #pragma unroll
            for (int i = 0; i < CH; ++i) p[i] = p1ring[base + i][lane];
            #pragma unroll
            for (int i = 0; i < CH; ++i) {
                const int t = k * CH + i;
                const float4* hp = (const float4*)h1buf[(t + 1) & 1];
                v2f ac0 = v2f{p[i], 0.f}, ac1 = v2f{0.f, 0.f};
                #pragma unroll
                for (int q = 0; q < 16; ++q) {
                    float4 hv = hp[q];
                    ac0 = __builtin_elementwise_fma(v2f{hv.x, hv.y}, w[2*q],   ac0);
                    ac1 = __builtin_elementwise_fma(v2f{hv.z, hv.w}, w[2*q+1], ac1);
                }
                h1buf[t & 1][lane] =
                    fast_tanh((ac0.x + ac1.x) + (ac0.y + ac1.y));
            }
            lds_fence();                           // p1 reads consumed
            if (lane == 0) vf[2] = k + 1;
        }
        // ---- MLP head: y = relu(h1 @ W1^T + b1) @ W2^T + b2 ----
        float r = 0.f;
        if (lane < 32) {
            float acc = b1[lane];
            const float* w1r = W1 + lane * HID;
            const float* hN  = h1buf[(TLEN - 1) & 1];
            #pragma unroll
            for (int j = 0; j < HID; ++j) acc = fmaf(w1r[j], hN[j], acc);
            r = fmaxf(acc, 0.f) * W2[lane];
        }
        #pragma unroll
        for (int off = 32; off > 0; off >>= 1) r += __shfl_down(r, off);
        if (lane == 0) out[b] = r + b2[0];
    }
}

extern "C" void kernel_launch(void* const* d_in, const int* in_sizes, int n_in,
                              void* d_out, int out_size, void* d_ws, size_t ws_size,
                              hipStream_t stream)
{
    const int*   x    = (const int*)d_in[0];
    const float* emb  = (const float*)d_in[1];
    const float* Wih0 = (const float*)d_in[2];
    const float* Whh0 = (const float*)d_in[3];
    const float* bih0 = (const float*)d_in[4];
    const float* bhh0 = (const float*)d_in[5];
    const float* Wih1 = (const float*)d_in[6];
    const float* Whh1 = (const float*)d_in[7];
    const float* bih1 = (const float*)d_in[8];
    const float* bhh1 = (const float*)d_in[9];
    const float* W1   = (const float*)d_in[10];
    const float* b1   = (const float*)d_in[11];
    const float* W2   = (const float*)d_in[12];
    const float* b2   = (const float*)d_in[13];

    float* P0 = (float*)d_ws;   // 512*64*4 = 128 KiB scratch

    hipLaunchKernelGGL(p0_kernel, dim3(VOCAB), dim3(HID), 0, stream,
                       emb, Wih0, bih0, bhh0, P0);
    hipLaunchKernelGGL(rnn_kernel, dim3(BATCH), dim3(192), 0, stream,
                       x, P0, Whh0, Wih1, Whh1, bih1, bhh1,
                       W1, b1, W2, b2, (float*)d_out);
}

// Round 8
// 374.572 us; speedup vs baseline: 1.5550x; 1.0506x over previous
//
#include <hip/hip_runtime.h>
#include <hip/hip_bf16.h>

#define VOCAB 512
#define EMB   128
#define HID   64
#define BATCH 256
#define TLEN  1024
#define CH    16              // steps per chunk
#define NCH   (TLEN / CH)     // 64 chunks
#define RS    128             // ring depth in steps (8 chunks)
#define RCH   (RS / CH)       // 8 chunks per ring

typedef float v2f __attribute__((ext_vector_type(2)));

__device__ __forceinline__ float fast_tanh(float x) {
    // tanh(x) = 1 - 2/(exp(2x)+1); exact at both saturated ends.
    float e = __expf(2.0f * x);
    return 1.0f - 2.0f / (e + 1.0f);
}

// LDS-only fence: drains DS queue WITHOUT vmcnt -> global prefetches live on.
__device__ __forceinline__ void lds_fence() {
    asm volatile("s_waitcnt lgkmcnt(0)" ::: "memory");
}
__device__ __forceinline__ void compiler_fence() {
    asm volatile("" ::: "memory");
}
__device__ __forceinline__ void nap() { __builtin_amdgcn_s_sleep(1); }

// dot(w_row, h_broadcast) + init with FOUR 8-deep v2f accumulator chains
// (R5 used two 16-deep chains; chain latency halves).
__device__ __forceinline__ float dot64_lds(const float4* hp, const v2f* w,
                                           float init) {
    v2f a0 = v2f{init, 0.f}, a1 = v2f{0.f, 0.f};
    v2f a2 = v2f{0.f, 0.f},  a3 = v2f{0.f, 0.f};
    #pragma unroll
    for (int q = 0; q < 8; ++q) {
        float4 u = hp[2 * q];
        float4 v = hp[2 * q + 1];
        a0 = __builtin_elementwise_fma(v2f{u.x, u.y}, w[4 * q + 0], a0);
        a1 = __builtin_elementwise_fma(v2f{u.z, u.w}, w[4 * q + 1], a1);
        a2 = __builtin_elementwise_fma(v2f{v.x, v.y}, w[4 * q + 2], a2);
        a3 = __builtin_elementwise_fma(v2f{v.z, v.w}, w[4 * q + 3], a3);
    }
    return ((a0.x + a0.y) + (a1.x + a1.y)) + ((a2.x + a2.y) + (a3.x + a3.y));
}

// ---------------------------------------------------------------------------
// Kernel 1: P0[v][i] = sum_e emb[v][e]*Wih0[i][e] + bih0[i] + bhh0[i]  (fp32)
// ---------------------------------------------------------------------------
__global__ void __launch_bounds__(64) p0_kernel(
    const float* __restrict__ emb,
    const float* __restrict__ wih0,
    const float* __restrict__ bih0,
    const float* __restrict__ bhh0,
    float* __restrict__ P0)
{
    const int v = blockIdx.x;
    const int i = threadIdx.x;
    const float4* er = (const float4*)(emb  + v * EMB);
    const float4* wr = (const float4*)(wih0 + i * EMB);
    float a0 = 0.f, a1 = 0.f, a2 = 0.f, a3 = 0.f;
    #pragma unroll
    for (int k = 0; k < EMB / 4; ++k) {
        float4 e4 = er[k];
        float4 w4 = wr[k];
        a0 = fmaf(e4.x, w4.x, a0);
        a1 = fmaf(e4.y, w4.y, a1);
        a2 = fmaf(e4.z, w4.z, a2);
        a3 = fmaf(e4.w, w4.w, a3);
    }
    P0[v * HID + i] = (a0 + a1) + (a2 + a3) + bih0[i] + bhh0[i];
}

// ---------------------------------------------------------------------------
// Kernel 2: decoupled 3-wave pipeline. R8 change: wave0's steady loop has
// ZERO scalar/SMEM ops — x values and P0 rows prefetched a full chunk ahead
// into VGPRs via vector loads (vmcnt), so per-step lgkmcnt counts only DS
// ops and the compiler's fine-grained waits never entangle the h-broadcast
// reads with x-load latency (R5/R7 post-mortem: s_load shares lgkmcnt with
// DS and completes out-of-order -> conservative full drains on the chain).
//   wave0: h0[t] = tanh(P0[x[t]] + Whh0 h0[t-1])      (recurrent)
//   wave1: p1[t] = b1 + Wih1 h0[t]                     (no recurrence)
//   wave2: h1[t] = tanh(p1[t] + Whh1 h1[t-1])          (recurrent)
// ---------------------------------------------------------------------------
__global__ void __launch_bounds__(192, 1) rnn_kernel(
    const int*   __restrict__ xs,
    const float* __restrict__ P0,
    const float* __restrict__ Whh0,
    const float* __restrict__ Wih1,
    const float* __restrict__ Whh1,
    const float* __restrict__ bih1,
    const float* __restrict__ bhh1,
    const float* __restrict__ W1,
    const float* __restrict__ b1,
    const float* __restrict__ W2,
    const float* __restrict__ b2,
    float*       __restrict__ out)
{
    __shared__ float h0ring[RS][HID];   // 32 KiB
    __shared__ float p1ring[RS][HID];   // 32 KiB
    __shared__ float h1buf[2][HID];
    __shared__ int   flags[3];

    const int b    = blockIdx.x;
    const int tid  = threadIdx.x;
    const int wv   = tid >> 6;
    const int lane = tid & 63;

    const int* xrow = xs + b * TLEN;
    // vz == 0, but opaque to uniformity analysis -> forces VECTOR loads
    // (vmcnt path) for the x reads instead of s_load (lgkmcnt path).
    const int vz = (int)__builtin_amdgcn_mbcnt_lo(0u, 0u);

    if (wv == 0) {
        h0ring[RS - 1][lane] = 0.f;      // h0[-1] = 0
    } else if (wv == 2) {
        h1buf[0][lane] = 0.f;            // h1[-1] = 0
        h1buf[1][lane] = 0.f;
    }
    if (tid < 3) flags[tid] = 0;
    __syncthreads();                     // the ONLY barrier in the kernel

    // Per-wave weight row -> 32 packed v2f (64 VGPRs), loop-invariant.
    const float* wmat = (wv == 0) ? Whh0 : (wv == 1) ? Wih1 : Whh1;
    v2f w[32];
    {
        const float4* wr = (const float4*)(wmat + lane * HID);
        #pragma unroll
        for (int k = 0; k < 16; ++k) {
            float4 u = wr[k];
            w[2 * k]     = v2f{u.x, u.y};
            w[2 * k + 1] = v2f{u.z, u.w};
        }
    }

    volatile int* vf = (volatile int*)flags;

    if (wv == 0) {
        // ---- layer-0 recurrence, chunk-ahead VGPR prefetch pipeline ----
        // xv_old[i]: x indices of chunk k+1 (loaded at top of chunk k-1... )
        // a_old[i] : P0 rows for the CURRENT chunk (gathered last chunk top)
        int   xv_old[CH];
        float a_old[CH];
        #pragma unroll
        for (int i = 0; i < CH; ++i)
            xv_old[i] = xrow[CH + i + vz] & (VOCAB - 1);    // x of chunk 1
        #pragma unroll
        for (int i = 0; i < CH; ++i)
            a_old[i] = P0[(xrow[i + vz] & (VOCAB - 1)) * HID + lane]; // chunk 0

        #pragma unroll 1
        for (int k = 0; k < NCH; ++k) {
            if (k >= RCH) {                       // slot reuse guard
                while (vf[1] < k - (RCH - 1)) nap();
                compiler_fence();
            }
            // prefetch x of chunk k+2 and gather P0 rows of chunk k+1 —
            // all vector loads (vmcnt), consumed ~1 chunk (>10k cyc) later
            const int  c2  = (k + 2 < NCH) ? (k + 2) : (NCH - 1);
            const int* xp  = xrow + c2 * CH;
            int   xv_new[CH];
            float a_new[CH];
            #pragma unroll
            for (int i = 0; i < CH; ++i)
                xv_new[i] = xp[i + vz] & (VOCAB - 1);
            #pragma unroll
            for (int i = 0; i < CH; ++i)
                a_new[i] = P0[xv_old[i] * HID + lane];

            const int base = (k & (RCH - 1)) * CH;
            #pragma unroll
            for (int i = 0; i < CH; ++i) {
                const float4* hp =
                    (const float4*)h0ring[(base + i - 1) & (RS - 1)];
                float z = dot64_lds(hp, w, a_old[i]);
                h0ring[base + i][lane] = fast_tanh(z);
            }
            lds_fence();                          // DS queue only, NOT vmcnt
            if (lane == 0) vf[0] = k + 1;

            #pragma unroll
            for (int i = 0; i < CH; ++i) { a_old[i] = a_new[i]; xv_old[i] = xv_new[i]; }
        }
    } else if (wv == 1) {
        // ---- layer-1 input projection (no recurrence: pure throughput) ----
        const float b1s = bih1[lane] + bhh1[lane];
        #pragma unroll 1
        for (int k = 0; k < NCH; ++k) {
            while (vf[0] < k + 1) nap();
            if (k >= RCH) { while (vf[2] < k - (RCH - 1)) nap(); }
            compiler_fence();
            const int base = (k & (RCH - 1)) * CH;
            #pragma unroll
            for (int i = 0; i < CH; ++i) {
                const float4* hp = (const float4*)h0ring[base + i];
                p1ring[base + i][lane] = dot64_lds(hp, w, b1s);
            }
            lds_fence();
            if (lane == 0) vf[1] = k + 1;
        }
    } else {
        // ---- layer-1 recurrence (pure DS loop — already lgkm-clean) ----
        #pragma unroll 1
        for (int k = 0; k < NCH; ++k) {
            while (vf[1] < k + 1) nap();
            compiler_fence();
            const int base = (k & (RCH - 1)) * CH;
            float p[CH];                           // bulk chunk prefetch (DS)
            #pragma unroll
            for (int i = 0; i < CH; ++i) p[i] = p1ring[base + i][lane];
            #pragma unroll
            for (int i = 0; i < CH; ++i) {
                const int t = k * CH + i;
                const float4* hp = (const float4*)h1buf[(t + 1) & 1];
                float z = dot64_lds(hp, w, p[i]);
                h1buf[t & 1][lane] = fast_tanh(z);
            }
            lds_fence();                           // p1 reads consumed
            if (lane == 0) vf[2] = k + 1;
        }
        // ---- MLP head: y = relu(h1 @ W1^T + b1) @ W2^T + b2 ----
        float r = 0.f;
        if (lane < 32) {
            float acc = b1[lane];
            const float* w1r = W1 + lane * HID;
            const float* hN  = h1buf[(TLEN - 1) & 1];
            #pragma unroll
            for (int j = 0; j < HID; ++j) acc = fmaf(w1r[j], hN[j], acc);
            r = fmaxf(acc, 0.f) * W2[lane];
        }
        #pragma unroll
        for (int off = 32; off > 0; off >>= 1) r += __shfl_down(r, off);
        if (lane == 0) out[b] = r + b2[0];
    }
}

extern "C" void kernel_launch(void* const* d_in, const int* in_sizes, int n_in,
                              void* d_out, int out_size, void* d_ws, size_t ws_size,
                              hipStream_t stream)
{
    const int*   x    = (const int*)d_in[0];
    const float* emb  = (const float*)d_in[1];
    const float* Wih0 = (const float*)d_in[2];
    const float* Whh0 = (const float*)d_in[3];
    const float* bih0 = (const float*)d_in[4];
    const float* bhh0 = (const float*)d_in[5];
    const float* Wih1 = (const float*)d_in[6];
    const float* Whh1 = (const float*)d_in[7];
    const float* bih1 = (const float*)d_in[8];
    const float* bhh1 = (const float*)d_in[9];
    const float* W1   = (const float*)d_in[10];
    const float* b1   = (const float*)d_in[11];
    const float* W2   = (const float*)d_in[12];
    const float* b2   = (const float*)d_in[13];

    float* P0 = (float*)d_ws;   // 512*64*4 = 128 KiB scratch

    hipLaunchKernelGGL(p0_kernel, dim3(VOCAB), dim3(HID), 0, stream,
                       emb, Wih0, bih0, bhh0, P0);
    hipLaunchKernelGGL(rnn_kernel, dim3(BATCH), dim3(192), 0, stream,
                       x, P0, Whh0, Wih1, Whh1, bih1, bhh1,
                       W1, b1, W2, b2, (float*)d_out);
}